// Round 5
// baseline (528.055 us; speedup 1.0000x reference)
//
#include <hip/hip_runtime.h>
#include <math.h>

#define N_NODES 100000
#define N_EDGES 1600000
#define D_IN 256
#define D_OUT 128

// ---- workspace layout (bytes) ------------------------------------------
#define OFF_SUPPORT 0
#define OFF_COUNTS  51200000
#define OFF_CSREV   51600008
#define OFF_BSUMS   64400008
#define OFF_WTHI    64400416
#define OFF_WTLO    64465952

#define SCAN_CHUNK  1024
#define SCAN_BLOCKS ((N_NODES + SCAN_CHUNK - 1) / SCAN_CHUNK)  // 98

#define GB 128                                   // node rows per GEMM tile
#define GEMM_BLOCKS ((N_NODES + GB - 1) / GB)    // 782
#define EDGE_BLOCKS ((N_EDGES + 255) / 256)      // 6250
#define WCONV_BLOCKS ((D_IN * D_OUT) / 256)      // 128

typedef __attribute__((ext_vector_type(8))) short s8v;   // 8 bf16 = 4 VGPR
typedef __attribute__((ext_vector_type(4))) float f4v;   // mfma acc

__device__ __forceinline__ short f2bf(float x) {   // RNE fp32 -> bf16 bits
  unsigned u = __float_as_uint(x);
  unsigned r = u + 0x7FFF + ((u >> 16) & 1);
  return (short)(r >> 16);
}
__device__ __forceinline__ float bf2f(short h) {
  return __uint_as_float(((unsigned)(unsigned short)h) << 16);
}

// split 8 fp32 into bf16 hi/lo fragments (in-register)
__device__ __forceinline__ void cvt8(float4 a, float4 b, s8v& h, s8v& l) {
  float f[8] = {a.x, a.y, a.z, a.w, b.x, b.y, b.z, b.w};
#pragma unroll
  for (int i = 0; i < 8; i++) {
    short hh = f2bf(f[i]);
    h[i] = hh;
    l[i] = f2bf(f[i] - bf2f(hh));
  }
}

typedef const float __attribute__((address_space(1)))* gas1f;
typedef float __attribute__((address_space(3)))* las3f;
__device__ __forceinline__ void gload_lds16(const float* g, float* l) {
  __builtin_amdgcn_global_load_lds((gas1f)g, (las3f)l, 16, 0, 0);
}

// ---------------------------------------------------------------------------
// K_prep: wconv (128 blocks) || edge histogram count (6250 blocks).
// No LDS, no pos_e -> hist runs at full occupancy with zero phantom LDS.
// counts[] zeroed by hipMemsetAsync before this dispatch.
// ---------------------------------------------------------------------------
__global__ __launch_bounds__(256) void prep_kernel(
    const float* __restrict__ W, short* __restrict__ wt_hi,
    short* __restrict__ wt_lo, const int* __restrict__ erow,
    int* __restrict__ counts) {
  if (blockIdx.x < WCONV_BLOCKS) {
    int idx = blockIdx.x * 256 + threadIdx.x;   // 0..32767
    int k = idx >> 7;
    int n = idx & 127;
    float v = W[idx];
    short h = f2bf(v);
    wt_hi[n * 256 + k] = h;
    wt_lo[n * 256 + k] = f2bf(v - bf2f(h));
  } else {
    int e = (blockIdx.x - WCONV_BLOCKS) * 256 + threadIdx.x;
    if (e < N_EDGES) atomicAdd(&counts[erow[e]], 1);
  }
}

// ---------------------------------------------------------------------------
// Little's-law GEMM body (verified round 3/4): barrier-free, 2-deep DMA
// pipeline, per-wave-private LDS slices, XOR-swizzled staging.
// Now a STANDALONE dispatch: no co-resident atomic traffic to poison the
// B-load / stage-DMA latency margins.
// ---------------------------------------------------------------------------
__device__ __forceinline__ void gemm_body(
    int gb, const float* __restrict__ input, const short* __restrict__ wt_hi,
    const short* __restrict__ wt_lo, const float* __restrict__ b,
    float* __restrict__ support) {
  __shared__ float Af[4][2][32][32];   // 32 KB: wave x dbuf x row x k
  const int t = threadIdx.x;
  const int lane = t & 63;
  const int wv = t >> 6;
  const int qm = lane & 15;
  const int quad = lane >> 4;
  const int node0 = gb * GB;

  const int srow = lane >> 3;          // 0..7
  const int gc = (lane & 7) ^ srow;    // swizzled 16B-chunk in source row

  auto stage = [&](int kt, int buf) {
#pragma unroll
    for (int j = 0; j < 4; ++j) {
      int nd = node0 + wv * 32 + j * 8 + srow;
      if (nd > N_NODES - 1) nd = N_NODES - 1;   // clamp; garbage never stored
      gload_lds16(input + (size_t)nd * D_IN + kt * 32 + gc * 4,
                  &Af[wv][buf][j * 8][0]);
    }
  };

  stage(0, 0);
  stage(1, 1);

  f4v acc[2][8];
#pragma unroll
  for (int mt = 0; mt < 2; mt++)
#pragma unroll
    for (int nt = 0; nt < 8; nt++) acc[mt][nt] = (f4v){0.f, 0.f, 0.f, 0.f};

  const int p0 = (2 * quad) ^ (qm & 7);      // physical chunk of logical 2q
  const int p1 = (2 * quad + 1) ^ (qm & 7);  // physical chunk of logical 2q+1

#pragma unroll
  for (int kt = 0; kt < 8; ++kt) {
    const int cb = kt & 1;
    asm volatile("s_waitcnt vmcnt(4)" ::: "memory");
    float4 x00 = *(const float4*)&Af[wv][cb][qm][p0 * 4];
    float4 x01 = *(const float4*)&Af[wv][cb][qm][p1 * 4];
    float4 x10 = *(const float4*)&Af[wv][cb][qm + 16][p0 * 4];
    float4 x11 = *(const float4*)&Af[wv][cb][qm + 16][p1 * 4];
    asm volatile("s_waitcnt lgkmcnt(0)" ::: "memory");
    __builtin_amdgcn_sched_barrier(0);

    const int koff = kt * 32 + quad * 8;
    s8v bh[8], bl[8];
#pragma unroll
    for (int nt = 0; nt < 8; ++nt) {
      size_t bo = (size_t)(nt * 16 + qm) * 256 + koff;
      bh[nt] = *(const s8v*)(wt_hi + bo);
      bl[nt] = *(const s8v*)(wt_lo + bo);
    }
    __builtin_amdgcn_sched_barrier(0);
    if (kt < 6) stage(kt + 2, cb);       // newest in queue -> survives B-waits
    __builtin_amdgcn_sched_barrier(0);

    s8v ah0, al0, ah1, al1;
    cvt8(x00, x01, ah0, al0);
    cvt8(x10, x11, ah1, al1);
#pragma unroll
    for (int nt = 0; nt < 8; ++nt) {
      acc[0][nt] = __builtin_amdgcn_mfma_f32_16x16x32_bf16(ah0, bh[nt], acc[0][nt], 0, 0, 0);
      acc[0][nt] = __builtin_amdgcn_mfma_f32_16x16x32_bf16(ah0, bl[nt], acc[0][nt], 0, 0, 0);
      acc[0][nt] = __builtin_amdgcn_mfma_f32_16x16x32_bf16(al0, bh[nt], acc[0][nt], 0, 0, 0);
      acc[1][nt] = __builtin_amdgcn_mfma_f32_16x16x32_bf16(ah1, bh[nt], acc[1][nt], 0, 0, 0);
      acc[1][nt] = __builtin_amdgcn_mfma_f32_16x16x32_bf16(ah1, bl[nt], acc[1][nt], 0, 0, 0);
      acc[1][nt] = __builtin_amdgcn_mfma_f32_16x16x32_bf16(al1, bh[nt], acc[1][nt], 0, 0, 0);
    }
  }

  float bias[8];
#pragma unroll
  for (int nt = 0; nt < 8; nt++) bias[nt] = b[nt * 16 + qm];
#pragma unroll
  for (int mt = 0; mt < 2; mt++) {
#pragma unroll
    for (int nt = 0; nt < 8; nt++) {
      int col = nt * 16 + qm;
#pragma unroll
      for (int r = 0; r < 4; r++) {
        int node = node0 + wv * 32 + mt * 16 + quad * 4 + r;
        if (node < N_NODES)
          support[(size_t)node * D_OUT + col] = acc[mt][nt][r] + bias[nt];
      }
    }
  }
}

__global__ __launch_bounds__(256, 3) void gemm_kernel(
    const float* __restrict__ input, const short* __restrict__ wt_hi,
    const short* __restrict__ wt_lo, const float* __restrict__ b,
    float* __restrict__ support) {
  gemm_body(blockIdx.x, input, wt_hi, wt_lo, b, support);
}

// ---------------------------------------------------------------------------
// K_build (fused): slot = offsets[row] + fill-rank via second atomic round.
// pos_e eliminated entirely (saves 12.8 MB of write+read traffic).
// Within-row order = atomic arrival order, same as the old pos_e scheme.
// ---------------------------------------------------------------------------
__global__ __launch_bounds__(256) void build_kernel(
    const int* __restrict__ erow, const int* __restrict__ ecol,
    const float* __restrict__ eval, const int* __restrict__ offsets,
    int* __restrict__ fill, int2* __restrict__ csr_ev) {
  int e = blockIdx.x * 256 + threadIdx.x;
  if (e < N_EDGES) {
    int r = erow[e];
    int idx = offsets[r] + atomicAdd(&fill[r], 1);
    csr_ev[idx] = make_int2(ecol[e], __float_as_int(eval[e]));
  }
}

// ---------------------------------------------------------------------------
// 3-phase exclusive scan over counts (verified); phase3 also zeroes fill[]
// ---------------------------------------------------------------------------
__global__ __launch_bounds__(256) void scan_phase1(const int* __restrict__ counts,
                                                   int* __restrict__ bsums) {
  __shared__ int ts[256];
  int t = threadIdx.x;
  int idx0 = blockIdx.x * SCAN_CHUNK + t * 4;
  int s = 0;
#pragma unroll
  for (int i = 0; i < 4; i++)
    if (idx0 + i < N_NODES) s += counts[idx0 + i];
  ts[t] = s;
  __syncthreads();
#pragma unroll
  for (int off = 128; off > 0; off >>= 1) {
    if (t < off) ts[t] += ts[t + off];
    __syncthreads();
  }
  if (t == 0) bsums[blockIdx.x] = ts[0];
}

__global__ __launch_bounds__(128) void scan_phase2(int* __restrict__ bsums) {
  __shared__ int s[128];
  int t = threadIdx.x;
  int v = (t < SCAN_BLOCKS) ? bsums[t] : 0;
  s[t] = v;
  __syncthreads();
#pragma unroll
  for (int off = 1; off < 128; off <<= 1) {
    int x = (t >= off) ? s[t - off] : 0;
    __syncthreads();
    s[t] += x;
    __syncthreads();
  }
  if (t < SCAN_BLOCKS) bsums[t] = s[t] - v;  // exclusive
}

__global__ __launch_bounds__(256) void scan_phase3(int* __restrict__ counts,
                                                   const int* __restrict__ bsums,
                                                   int* __restrict__ fill) {
  __shared__ int ts[256];
  int t = threadIdx.x;
  int b = blockIdx.x;
  int idx0 = b * SCAN_CHUNK + t * 4;
  int v[4];
  int s = 0;
#pragma unroll
  for (int i = 0; i < 4; i++) {
    v[i] = (idx0 + i < N_NODES) ? counts[idx0 + i] : 0;
    s += v[i];
  }
  ts[t] = s;
  __syncthreads();
#pragma unroll
  for (int off = 1; off < 256; off <<= 1) {
    int x = (t >= off) ? ts[t - off] : 0;
    __syncthreads();
    ts[t] += x;
    __syncthreads();
  }
  int run = bsums[b] + ts[t] - s;
#pragma unroll
  for (int i = 0; i < 4; i++) {
    int idx = idx0 + i;
    if (idx < N_NODES) {
      counts[idx] = run;
      fill[idx] = 0;
    }
    run += v[i];
  }
  if (b == 0 && t == 0) counts[N_NODES] = N_EDGES;
}

// ---------------------------------------------------------------------------
// Gather-aggregate + fused tanh (verified round 4).  32 lanes x float4 per
// row; always-8-wide predicated batches + software-pipelined edge prefetch.
// ---------------------------------------------------------------------------
__global__ __launch_bounds__(256) void agg_kernel(
    const int* __restrict__ offsets, const int2* __restrict__ csr_ev,
    const float* __restrict__ support, float* __restrict__ out) {
  int r = blockIdx.x * 8 + (threadIdx.x >> 5);
  int l4 = (threadIdx.x & 31) * 4;          // feature quad
  int beg = offsets[r];
  int end = offsets[r + 1];
  float4 acc = make_float4(0.f, 0.f, 0.f, 0.f);

  if (end > beg) {
    int2 e[8], en[8];
#pragma unroll
    for (int u = 0; u < 8; u++) {           // prologue batch (predicated)
      int idx = beg + u;
      int c = idx < end ? idx : end - 1;
      e[u] = csr_ev[c];
      if (idx >= end) e[u].y = 0;           // val := 0.0f
    }
    for (int j = beg; j < end; j += 8) {
      int jn = j + 8;
      if (jn < end) {                       // prefetch next batch
#pragma unroll
        for (int u = 0; u < 8; u++) {
          int idx = jn + u;
          int c = idx < end ? idx : end - 1;
          en[u] = csr_ev[c];
          if (idx >= end) en[u].y = 0;
        }
      }
      float4 s[8];
#pragma unroll
      for (int u = 0; u < 8; u++)
        s[u] = *(const float4*)(support + (size_t)e[u].x * D_OUT + l4);
#pragma unroll
      for (int u = 0; u < 8; u++) {
        float v = __int_as_float(e[u].y);
        acc.x = fmaf(v, s[u].x, acc.x);
        acc.y = fmaf(v, s[u].y, acc.y);
        acc.z = fmaf(v, s[u].z, acc.z);
        acc.w = fmaf(v, s[u].w, acc.w);
      }
#pragma unroll
      for (int u = 0; u < 8; u++) e[u] = en[u];
    }
  }
  *(float4*)(out + (size_t)r * D_OUT + l4) =
      make_float4(tanhf(acc.x), tanhf(acc.y), tanhf(acc.z), tanhf(acc.w));
}

extern "C" void kernel_launch(void* const* d_in, const int* in_sizes, int n_in,
                              void* d_out, int out_size, void* d_ws, size_t ws_size,
                              hipStream_t stream) {
  const float* input = (const float*)d_in[0];
  const int* erow = (const int*)d_in[1];
  const int* ecol = (const int*)d_in[2];
  const float* eval = (const float*)d_in[3];
  const float* W = (const float*)d_in[4];
  const float* b = (const float*)d_in[5];
  float* out = (float*)d_out;

  char* ws = (char*)d_ws;
  float* support = (float*)(ws + OFF_SUPPORT);
  int* counts = (int*)(ws + OFF_COUNTS);  // becomes offsets after scan
  int2* csr_ev = (int2*)(ws + OFF_CSREV);
  int* bsums = (int*)(ws + OFF_BSUMS);
  short* wt_hi = (short*)(ws + OFF_WTHI);
  short* wt_lo = (short*)(ws + OFF_WTLO);
  int* fill = (int*)d_out;  // d_out as scratch; agg overwrites it last

  hipMemsetAsync(ws + OFF_COUNTS, 0, (size_t)(N_NODES + 1) * 4, stream);

  // K_prep: wconv || histogram count (no LDS, full occupancy)
  hipLaunchKernelGGL(prep_kernel, dim3(WCONV_BLOCKS + EDGE_BLOCKS), dim3(256),
                     0, stream, W, wt_hi, wt_lo, erow, counts);
  // K_gemm: standalone MFMA GEMM (no atomic interference)
  hipLaunchKernelGGL(gemm_kernel, dim3(GEMM_BLOCKS), dim3(256), 0, stream,
                     input, wt_hi, wt_lo, b, support);
  // exclusive scan: counts -> offsets (+ fill zeroing)
  hipLaunchKernelGGL(scan_phase1, dim3(SCAN_BLOCKS), dim3(256), 0, stream,
                     counts, bsums);
  hipLaunchKernelGGL(scan_phase2, dim3(1), dim3(128), 0, stream, bsums);
  hipLaunchKernelGGL(scan_phase3, dim3(SCAN_BLOCKS), dim3(256), 0, stream,
                     counts, bsums, fill);
  // K_build: fused rank + scatter (pos_e eliminated)
  hipLaunchKernelGGL(build_kernel, dim3(EDGE_BLOCKS), dim3(256), 0, stream,
                     erow, ecol, eval, counts, fill, csr_ev);
  // out = tanh(A_csr * support)
  hipLaunchKernelGGL(agg_kernel, dim3(N_NODES / 8), dim3(256), 0, stream,
                     counts, csr_ev, support, out);
}

// Round 6
// 464.514 us; speedup vs baseline: 1.1368x; 1.1368x over previous
//
#include <hip/hip_runtime.h>
#include <math.h>

#define N_NODES 100000
#define N_EDGES 1600000
#define D_IN 256
#define D_OUT 128

// ---- workspace layout (bytes) ------------------------------------------
#define OFF_SUPPORT 0
#define OFF_COUNTS  51200000
#define OFF_CSREV   51600008
#define OFF_BSUMS   64400008
#define OFF_WTHI    64400416
#define OFF_WTLO    64465952

#define SCAN_CHUNK  1024
#define SCAN_BLOCKS ((N_NODES + SCAN_CHUNK - 1) / SCAN_CHUNK)  // 98

#define GB 128                                   // node rows per GEMM tile
#define GEMM_BLOCKS ((N_NODES + GB - 1) / GB)    // 782
#define EDGE_BLOCKS ((N_EDGES + 255) / 256)      // 6250
#define WCONV_BLOCKS ((D_IN * D_OUT) / 256)      // 128

typedef __attribute__((ext_vector_type(8))) short s8v;   // 8 bf16 = 4 VGPR
typedef __attribute__((ext_vector_type(4))) float f4v;   // mfma acc

__device__ __forceinline__ short f2bf(float x) {   // RNE fp32 -> bf16 bits
  unsigned u = __float_as_uint(x);
  unsigned r = u + 0x7FFF + ((u >> 16) & 1);
  return (short)(r >> 16);
}
__device__ __forceinline__ float bf2f(short h) {
  return __uint_as_float(((unsigned)(unsigned short)h) << 16);
}

// split 8 fp32 into bf16 hi/lo fragments (in-register)
__device__ __forceinline__ void cvt8(float4 a, float4 b, s8v& h, s8v& l) {
  float f[8] = {a.x, a.y, a.z, a.w, b.x, b.y, b.z, b.w};
#pragma unroll
  for (int i = 0; i < 8; i++) {
    short hh = f2bf(f[i]);
    h[i] = hh;
    l[i] = f2bf(f[i] - bf2f(hh));
  }
}

__device__ __forceinline__ void gload_lds16(const void* g, void* l) {
  __builtin_amdgcn_global_load_lds(
      (const __attribute__((address_space(1))) void*)g,
      (__attribute__((address_space(3))) void*)l, 16, 0, 0);
}

#define VMW(N)                                             \
  asm volatile("s_waitcnt vmcnt(" #N ")" ::: "memory");    \
  __builtin_amdgcn_sched_barrier(0)
#define SBAR()                    \
  __builtin_amdgcn_s_barrier();   \
  __builtin_amdgcn_sched_barrier(0)

// ---------------------------------------------------------------------------
// K_prep: wconv (128 blocks) || edge histogram count (6250 blocks).
// ---------------------------------------------------------------------------
__global__ __launch_bounds__(256) void prep_kernel(
    const float* __restrict__ W, short* __restrict__ wt_hi,
    short* __restrict__ wt_lo, const int* __restrict__ erow,
    int* __restrict__ counts) {
  if (blockIdx.x < WCONV_BLOCKS) {
    int idx = blockIdx.x * 256 + threadIdx.x;   // 0..32767
    int k = idx >> 7;
    int n = idx & 127;
    float v = W[idx];
    short h = f2bf(v);
    wt_hi[n * 256 + k] = h;
    wt_lo[n * 256 + k] = f2bf(v - bf2f(h));
  } else {
    int e = (blockIdx.x - WCONV_BLOCKS) * 256 + threadIdx.x;
    if (e < N_EDGES) atomicAdd(&counts[erow[e]], 1);
  }
}

// ---------------------------------------------------------------------------
// GEMM v6: support = X*W + b.
//   The serializer in v1-v5: B loaded from global INSIDE the k-loop; the
//   compiler's pre-MFMA vmcnt wait for B forces (in-order retirement) every
//   older A load/DMA to retire -> A pipeline cover capped at ~1 iteration.
//   Fix: B lives in LDS (32KB per K-quarter, double-buffered, DMA'd with a
//   2-quarter lead); per-step B consumption is ds_read (lgkm domain, does
//   NOT drain vmcnt). A = direct per-lane float4 loads, 3-deep register
//   pipeline. Fully unrolled 8 steps with exact counted vmcnt gates:
//     8,16,8,16,8,16,4,0  (A cover = 3 steps, B cover = 2 steps)
//   Raw s_barrier only (never __syncthreads: it drains vmcnt to 0).
//   B ds_reads conflict-free via XOR swizzle baked into the per-lane DMA
//   SOURCE address (LDS dest stays linear; rule: both-sides-or-neither).
// Fragment math identical to verified rounds -> same absmax.
// ---------------------------------------------------------------------------
__global__ __launch_bounds__(256, 2) void gemm_kernel(
    const float* __restrict__ input, const short* __restrict__ wt_hi,
    const short* __restrict__ wt_lo, const float* __restrict__ b,
    float* __restrict__ support) {
  __shared__ short Bh[2][128][64];   // 32 KB: parity x col x k-quarter
  __shared__ short Bl[2][128][64];   // 32 KB
  const int t = threadIdx.x;
  const int lane = t & 63;
  const int wv = t >> 6;
  const int qm = lane & 15;
  const int quad = lane >> 4;
  const int node0 = blockIdx.x * GB;

  int r0 = node0 + wv * 32 + qm;
  int r1 = r0 + 16;
  if (r0 > N_NODES - 1) r0 = N_NODES - 1;   // clamp; garbage never stored
  if (r1 > N_NODES - 1) r1 = N_NODES - 1;
  const float* a0p = input + (size_t)r0 * D_IN + quad * 8;
  const float* a1p = input + (size_t)r1 * D_IN + quad * 8;

  // B quarter-stage: wave wv fills rows [wv*32, wv*32+32) of parity p.
  // 8 DMAs/wave (4 hi + 4 lo).  Lane l -> LDS +l*16 (row l>>3, chunk l&7);
  // source chunk = (l&7) ^ (row&7)  -> swizzled layout from linear DMA.
  const int lrow = lane >> 3;
  const int lpc = lane & 7;
  auto stageB = [&](int q, int p) {
    const int rb = wv * 32;
#pragma unroll
    for (int j = 0; j < 4; ++j) {
      int n = rb + j * 8 + lrow;
      int sc = lpc ^ (n & 7);
      const short* sh = wt_hi + (size_t)n * 256 + q * 64 + sc * 8;
      const short* sl = wt_lo + (size_t)n * 256 + q * 64 + sc * 8;
      gload_lds16(sh, &Bh[p][rb + j * 8][0]);
      gload_lds16(sl, &Bl[p][rb + j * 8][0]);
    }
  };

  float4 A0[4], A1[4], A2[4];
  auto loadA = [&](float4* d, int s) {
    d[0] = *(const float4*)(a0p + s * 32);
    d[1] = *(const float4*)(a0p + s * 32 + 4);
    d[2] = *(const float4*)(a1p + s * 32);
    d[3] = *(const float4*)(a1p + s * 32 + 4);
  };

  f4v acc[2][8];
#pragma unroll
  for (int mt = 0; mt < 2; mt++)
#pragma unroll
    for (int nt = 0; nt < 8; nt++) acc[mt][nt] = (f4v){0.f, 0.f, 0.f, 0.f};

  s8v ah0, al0, ah1, al1;
  auto cvtA = [&](const float4* X) {
    cvt8(X[0], X[1], ah0, al0);
    cvt8(X[2], X[3], ah1, al1);
  };
  auto mfma8 = [&](int p, int si) {
#pragma unroll
    for (int nt = 0; nt < 8; ++nt) {
      int n = nt * 16 + qm;
      int pc = (si * 4 + quad) ^ (n & 7);
      s8v bh = *(const s8v*)&Bh[p][n][pc * 8];
      s8v bl = *(const s8v*)&Bl[p][n][pc * 8];
      acc[0][nt] = __builtin_amdgcn_mfma_f32_16x16x32_bf16(ah0, bh, acc[0][nt], 0, 0, 0);
      acc[0][nt] = __builtin_amdgcn_mfma_f32_16x16x32_bf16(ah0, bl, acc[0][nt], 0, 0, 0);
      acc[0][nt] = __builtin_amdgcn_mfma_f32_16x16x32_bf16(al0, bh, acc[0][nt], 0, 0, 0);
      acc[1][nt] = __builtin_amdgcn_mfma_f32_16x16x32_bf16(ah1, bh, acc[1][nt], 0, 0, 0);
      acc[1][nt] = __builtin_amdgcn_mfma_f32_16x16x32_bf16(ah1, bl, acc[1][nt], 0, 0, 0);
      acc[1][nt] = __builtin_amdgcn_mfma_f32_16x16x32_bf16(al1, bh, acc[1][nt], 0, 0, 0);
    }
  };

  // ---- prologue: queue = [B0:8, A0:4, A1:4, A2:4] ----
  stageB(0, 0);
  loadA(A0, 0);
  loadA(A1, 1);
  loadA(A2, 2);
  // s0: gate B0+A0 (after-A0 = 8)
  VMW(8);
  SBAR();
  cvtA(A0);
  stageB(1, 1);
  loadA(A0, 3);
  mfma8(0, 0);
  // s1: gate A1 (after = A2+B1+A3 = 16)
  VMW(16);
  cvtA(A1);
  loadA(A1, 4);
  mfma8(0, 1);
  // s2: gate A2+B1 (after-B1 = A3+A4 = 8)
  VMW(8);
  SBAR();
  cvtA(A2);
  stageB(2, 0);
  loadA(A2, 5);
  mfma8(1, 0);
  // s3: gate A3 (after = A4+B2+A5 = 16)
  VMW(16);
  cvtA(A0);
  loadA(A0, 6);
  mfma8(1, 1);
  // s4: gate A4+B2 (after-B2 = A5+A6 = 8)
  VMW(8);
  SBAR();
  cvtA(A1);
  stageB(3, 1);
  loadA(A1, 7);
  mfma8(0, 0);
  // s5: gate A5 (after = A6+B3+A7 = 16)
  VMW(16);
  cvtA(A2);
  mfma8(0, 1);
  // s6: gate A6+B3 (after-B3 = A7 = 4)
  VMW(4);
  SBAR();
  cvtA(A0);
  mfma8(1, 0);
  // s7: gate A7
  VMW(0);
  cvtA(A1);
  mfma8(1, 1);

  // ---- epilogue ----
  float bias[8];
#pragma unroll
  for (int nt = 0; nt < 8; nt++) bias[nt] = b[nt * 16 + qm];
#pragma unroll
  for (int mt = 0; mt < 2; mt++) {
#pragma unroll
    for (int nt = 0; nt < 8; nt++) {
      int col = nt * 16 + qm;
#pragma unroll
      for (int r = 0; r < 4; r++) {
        int node = node0 + wv * 32 + mt * 16 + quad * 4 + r;
        if (node < N_NODES)
          support[(size_t)node * D_OUT + col] = acc[mt][nt][r] + bias[nt];
      }
    }
  }
}

// ---------------------------------------------------------------------------
// K_build (fused): slot = offsets[row] + fill-rank via second atomic round.
// ---------------------------------------------------------------------------
__global__ __launch_bounds__(256) void build_kernel(
    const int* __restrict__ erow, const int* __restrict__ ecol,
    const float* __restrict__ eval, const int* __restrict__ offsets,
    int* __restrict__ fill, int2* __restrict__ csr_ev) {
  int e = blockIdx.x * 256 + threadIdx.x;
  if (e < N_EDGES) {
    int r = erow[e];
    int idx = offsets[r] + atomicAdd(&fill[r], 1);
    csr_ev[idx] = make_int2(ecol[e], __float_as_int(eval[e]));
  }
}

// ---------------------------------------------------------------------------
// 3-phase exclusive scan over counts (verified); phase3 also zeroes fill[]
// ---------------------------------------------------------------------------
__global__ __launch_bounds__(256) void scan_phase1(const int* __restrict__ counts,
                                                   int* __restrict__ bsums) {
  __shared__ int ts[256];
  int t = threadIdx.x;
  int idx0 = blockIdx.x * SCAN_CHUNK + t * 4;
  int s = 0;
#pragma unroll
  for (int i = 0; i < 4; i++)
    if (idx0 + i < N_NODES) s += counts[idx0 + i];
  ts[t] = s;
  __syncthreads();
#pragma unroll
  for (int off = 128; off > 0; off >>= 1) {
    if (t < off) ts[t] += ts[t + off];
    __syncthreads();
  }
  if (t == 0) bsums[blockIdx.x] = ts[0];
}

__global__ __launch_bounds__(128) void scan_phase2(int* __restrict__ bsums) {
  __shared__ int s[128];
  int t = threadIdx.x;
  int v = (t < SCAN_BLOCKS) ? bsums[t] : 0;
  s[t] = v;
  __syncthreads();
#pragma unroll
  for (int off = 1; off < 128; off <<= 1) {
    int x = (t >= off) ? s[t - off] : 0;
    __syncthreads();
    s[t] += x;
    __syncthreads();
  }
  if (t < SCAN_BLOCKS) bsums[t] = s[t] - v;  // exclusive
}

__global__ __launch_bounds__(256) void scan_phase3(int* __restrict__ counts,
                                                   const int* __restrict__ bsums,
                                                   int* __restrict__ fill) {
  __shared__ int ts[256];
  int t = threadIdx.x;
  int b = blockIdx.x;
  int idx0 = b * SCAN_CHUNK + t * 4;
  int v[4];
  int s = 0;
#pragma unroll
  for (int i = 0; i < 4; i++) {
    v[i] = (idx0 + i < N_NODES) ? counts[idx0 + i] : 0;
    s += v[i];
  }
  ts[t] = s;
  __syncthreads();
#pragma unroll
  for (int off = 1; off < 256; off <<= 1) {
    int x = (t >= off) ? ts[t - off] : 0;
    __syncthreads();
    ts[t] += x;
    __syncthreads();
  }
  int run = bsums[b] + ts[t] - s;
#pragma unroll
  for (int i = 0; i < 4; i++) {
    int idx = idx0 + i;
    if (idx < N_NODES) {
      counts[idx] = run;
      fill[idx] = 0;
    }
    run += v[i];
  }
  if (b == 0 && t == 0) counts[N_NODES] = N_EDGES;
}

// ---------------------------------------------------------------------------
// Gather-aggregate + fused tanh (verified round 4).
// ---------------------------------------------------------------------------
__global__ __launch_bounds__(256) void agg_kernel(
    const int* __restrict__ offsets, const int2* __restrict__ csr_ev,
    const float* __restrict__ support, float* __restrict__ out) {
  int r = blockIdx.x * 8 + (threadIdx.x >> 5);
  int l4 = (threadIdx.x & 31) * 4;          // feature quad
  int beg = offsets[r];
  int end = offsets[r + 1];
  float4 acc = make_float4(0.f, 0.f, 0.f, 0.f);

  if (end > beg) {
    int2 e[8], en[8];
#pragma unroll
    for (int u = 0; u < 8; u++) {           // prologue batch (predicated)
      int idx = beg + u;
      int c = idx < end ? idx : end - 1;
      e[u] = csr_ev[c];
      if (idx >= end) e[u].y = 0;           // val := 0.0f
    }
    for (int j = beg; j < end; j += 8) {
      int jn = j + 8;
      if (jn < end) {                       // prefetch next batch
#pragma unroll
        for (int u = 0; u < 8; u++) {
          int idx = jn + u;
          int c = idx < end ? idx : end - 1;
          en[u] = csr_ev[c];
          if (idx >= end) en[u].y = 0;
        }
      }
      float4 s[8];
#pragma unroll
      for (int u = 0; u < 8; u++)
        s[u] = *(const float4*)(support + (size_t)e[u].x * D_OUT + l4);
#pragma unroll
      for (int u = 0; u < 8; u++) {
        float v = __int_as_float(e[u].y);
        acc.x = fmaf(v, s[u].x, acc.x);
        acc.y = fmaf(v, s[u].y, acc.y);
        acc.z = fmaf(v, s[u].z, acc.z);
        acc.w = fmaf(v, s[u].w, acc.w);
      }
#pragma unroll
      for (int u = 0; u < 8; u++) e[u] = en[u];
    }
  }
  *(float4*)(out + (size_t)r * D_OUT + l4) =
      make_float4(tanhf(acc.x), tanhf(acc.y), tanhf(acc.z), tanhf(acc.w));
}

extern "C" void kernel_launch(void* const* d_in, const int* in_sizes, int n_in,
                              void* d_out, int out_size, void* d_ws, size_t ws_size,
                              hipStream_t stream) {
  const float* input = (const float*)d_in[0];
  const int* erow = (const int*)d_in[1];
  const int* ecol = (const int*)d_in[2];
  const float* eval = (const float*)d_in[3];
  const float* W = (const float*)d_in[4];
  const float* b = (const float*)d_in[5];
  float* out = (float*)d_out;

  char* ws = (char*)d_ws;
  float* support = (float*)(ws + OFF_SUPPORT);
  int* counts = (int*)(ws + OFF_COUNTS);  // becomes offsets after scan
  int2* csr_ev = (int2*)(ws + OFF_CSREV);
  int* bsums = (int*)(ws + OFF_BSUMS);
  short* wt_hi = (short*)(ws + OFF_WTHI);
  short* wt_lo = (short*)(ws + OFF_WTLO);
  int* fill = (int*)d_out;  // d_out as scratch; agg overwrites it last

  hipMemsetAsync(ws + OFF_COUNTS, 0, (size_t)(N_NODES + 1) * 4, stream);

  // K_prep: wconv || histogram count
  hipLaunchKernelGGL(prep_kernel, dim3(WCONV_BLOCKS + EDGE_BLOCKS), dim3(256),
                     0, stream, W, wt_hi, wt_lo, erow, counts);
  // K_gemm: B-in-LDS, pure-A vm stream, counted gates
  hipLaunchKernelGGL(gemm_kernel, dim3(GEMM_BLOCKS), dim3(256), 0, stream,
                     input, wt_hi, wt_lo, b, support);
  // exclusive scan: counts -> offsets (+ fill zeroing)
  hipLaunchKernelGGL(scan_phase1, dim3(SCAN_BLOCKS), dim3(256), 0, stream,
                     counts, bsums);
  hipLaunchKernelGGL(scan_phase2, dim3(1), dim3(128), 0, stream, bsums);
  hipLaunchKernelGGL(scan_phase3, dim3(SCAN_BLOCKS), dim3(256), 0, stream,
                     counts, bsums, fill);
  // K_build: fused rank + scatter
  hipLaunchKernelGGL(build_kernel, dim3(EDGE_BLOCKS), dim3(256), 0, stream,
                     erow, ecol, eval, counts, fill, csr_ev);
  // out = tanh(A_csr * support)
  hipLaunchKernelGGL(agg_kernel, dim3(N_NODES / 8), dim3(256), 0, stream,
                     counts, csr_ev, support, out);
}

// Round 7
// 422.446 us; speedup vs baseline: 1.2500x; 1.0996x over previous
//
#include <hip/hip_runtime.h>
#include <math.h>

#define N_NODES 100000
#define N_EDGES 1600000
#define D_IN 256
#define D_OUT 128

// ---- workspace layout (bytes) ------------------------------------------
#define OFF_SUPPORT 0
#define OFF_COUNTS  51200000
#define OFF_CSREV   51600008
#define OFF_BSUMS   64400008
#define OFF_WTHI    64400416
#define OFF_WTLO    64465952

#define SCAN_CHUNK  1024
#define SCAN_BLOCKS ((N_NODES + SCAN_CHUNK - 1) / SCAN_CHUNK)  // 98

#define GB 128                                   // node rows per GEMM tile
#define GEMM_BLOCKS ((N_NODES + GB - 1) / GB)    // 782
#define EDGE_BLOCKS ((N_EDGES + 255) / 256)      // 6250

typedef __attribute__((ext_vector_type(8))) short s8v;   // 8 bf16 = 4 VGPR
typedef __attribute__((ext_vector_type(4))) float f4v;   // mfma acc

__device__ __forceinline__ short f2bf(float x) {   // RNE fp32 -> bf16 bits
  unsigned u = __float_as_uint(x);
  unsigned r = u + 0x7FFF + ((u >> 16) & 1);
  return (short)(r >> 16);
}
__device__ __forceinline__ float bf2f(short h) {
  return __uint_as_float(((unsigned)(unsigned short)h) << 16);
}

// split 8 fp32 into bf16 hi/lo fragments (in-register)
__device__ __forceinline__ void cvt8(float4 a, float4 b, s8v& h, s8v& l) {
  float f[8] = {a.x, a.y, a.z, a.w, b.x, b.y, b.z, b.w};
#pragma unroll
  for (int i = 0; i < 8; i++) {
    short hh = f2bf(f[i]);
    h[i] = hh;
    l[i] = f2bf(f[i] - bf2f(hh));
  }
}

__device__ __forceinline__ void gload_lds16(const void* g, void* l) {
  __builtin_amdgcn_global_load_lds(
      (const __attribute__((address_space(1))) void*)g,
      (__attribute__((address_space(3))) void*)l, 16, 0, 0);
}

#define VMW(N)                                             \
  asm volatile("s_waitcnt vmcnt(" #N ")" ::: "memory");    \
  __builtin_amdgcn_sched_barrier(0)
#define SBAR()                    \
  __builtin_amdgcn_s_barrier();   \
  __builtin_amdgcn_sched_barrier(0)

// ---------------------------------------------------------------------------
// K0: W[k][n] fp32 -> wt_hi/wt_lo[n][k] bf16 split (once) + zero counts
// ---------------------------------------------------------------------------
__global__ __launch_bounds__(256) void wconv_kernel(
    const float* __restrict__ W, short* __restrict__ wt_hi,
    short* __restrict__ wt_lo, int* __restrict__ counts) {
  int idx = blockIdx.x * 256 + threadIdx.x;   // grid 128 -> 32768
  int k = idx >> 7;
  int n = idx & 127;
  float v = W[idx];
  short h = f2bf(v);
  wt_hi[n * 256 + k] = h;
  wt_lo[n * 256 + k] = f2bf(v - bf2f(h));
  for (int i = idx; i < N_NODES + 1; i += 32768) counts[i] = 0;
}

// ---------------------------------------------------------------------------
// GEMM v6 body (verified round 6, ~70 us standalone): B in LDS (ds_read =
// lgkm domain, does NOT drain vmcnt); A = direct float4 loads in a 3-deep
// register pipeline; fully unrolled with exact counted vmcnt gates
// 8,16,8,16,8,16,4,0; raw s_barrier only; B swizzled via DMA source addr.
// ---------------------------------------------------------------------------
__device__ __forceinline__ void gemm_body(
    int gb, const float* __restrict__ input, const short* __restrict__ wt_hi,
    const short* __restrict__ wt_lo, const float* __restrict__ b,
    float* __restrict__ support) {
  __shared__ short Bh[2][128][64];   // 32 KB: parity x col x k-quarter
  __shared__ short Bl[2][128][64];   // 32 KB
  const int t = threadIdx.x;
  const int lane = t & 63;
  const int wv = t >> 6;
  const int qm = lane & 15;
  const int quad = lane >> 4;
  const int node0 = gb * GB;

  int r0 = node0 + wv * 32 + qm;
  int r1 = r0 + 16;
  if (r0 > N_NODES - 1) r0 = N_NODES - 1;   // clamp; garbage never stored
  if (r1 > N_NODES - 1) r1 = N_NODES - 1;
  const float* a0p = input + (size_t)r0 * D_IN + quad * 8;
  const float* a1p = input + (size_t)r1 * D_IN + quad * 8;

  const int lrow = lane >> 3;
  const int lpc = lane & 7;
  auto stageB = [&](int q, int p) {
    const int rb = wv * 32;
#pragma unroll
    for (int j = 0; j < 4; ++j) {
      int n = rb + j * 8 + lrow;
      int sc = lpc ^ (n & 7);
      const short* sh = wt_hi + (size_t)n * 256 + q * 64 + sc * 8;
      const short* sl = wt_lo + (size_t)n * 256 + q * 64 + sc * 8;
      gload_lds16(sh, &Bh[p][rb + j * 8][0]);
      gload_lds16(sl, &Bl[p][rb + j * 8][0]);
    }
  };

  float4 A0[4], A1[4], A2[4];
  auto loadA = [&](float4* d, int s) {
    d[0] = *(const float4*)(a0p + s * 32);
    d[1] = *(const float4*)(a0p + s * 32 + 4);
    d[2] = *(const float4*)(a1p + s * 32);
    d[3] = *(const float4*)(a1p + s * 32 + 4);
  };

  f4v acc[2][8];
#pragma unroll
  for (int mt = 0; mt < 2; mt++)
#pragma unroll
    for (int nt = 0; nt < 8; nt++) acc[mt][nt] = (f4v){0.f, 0.f, 0.f, 0.f};

  s8v ah0, al0, ah1, al1;
  auto cvtA = [&](const float4* X) {
    cvt8(X[0], X[1], ah0, al0);
    cvt8(X[2], X[3], ah1, al1);
  };
  auto mfma8 = [&](int p, int si) {
#pragma unroll
    for (int nt = 0; nt < 8; ++nt) {
      int n = nt * 16 + qm;
      int pc = (si * 4 + quad) ^ (n & 7);
      s8v bh = *(const s8v*)&Bh[p][n][pc * 8];
      s8v bl = *(const s8v*)&Bl[p][n][pc * 8];
      acc[0][nt] = __builtin_amdgcn_mfma_f32_16x16x32_bf16(ah0, bh, acc[0][nt], 0, 0, 0);
      acc[0][nt] = __builtin_amdgcn_mfma_f32_16x16x32_bf16(ah0, bl, acc[0][nt], 0, 0, 0);
      acc[0][nt] = __builtin_amdgcn_mfma_f32_16x16x32_bf16(al0, bh, acc[0][nt], 0, 0, 0);
      acc[1][nt] = __builtin_amdgcn_mfma_f32_16x16x32_bf16(ah1, bh, acc[1][nt], 0, 0, 0);
      acc[1][nt] = __builtin_amdgcn_mfma_f32_16x16x32_bf16(ah1, bl, acc[1][nt], 0, 0, 0);
      acc[1][nt] = __builtin_amdgcn_mfma_f32_16x16x32_bf16(al1, bh, acc[1][nt], 0, 0, 0);
    }
  };

  // ---- prologue: queue = [B0:8, A0:4, A1:4, A2:4] ----
  stageB(0, 0);
  loadA(A0, 0);
  loadA(A1, 1);
  loadA(A2, 2);
  VMW(8);   // gate B0+A0
  SBAR();
  cvtA(A0);
  stageB(1, 1);
  loadA(A0, 3);
  mfma8(0, 0);
  VMW(16);  // gate A1
  cvtA(A1);
  loadA(A1, 4);
  mfma8(0, 1);
  VMW(8);   // gate A2+B1
  SBAR();
  cvtA(A2);
  stageB(2, 0);
  loadA(A2, 5);
  mfma8(1, 0);
  VMW(16);  // gate A3
  cvtA(A0);
  loadA(A0, 6);
  mfma8(1, 1);
  VMW(8);   // gate A4+B2
  SBAR();
  cvtA(A1);
  stageB(3, 1);
  loadA(A1, 7);
  mfma8(0, 0);
  VMW(16);  // gate A5
  cvtA(A2);
  mfma8(0, 1);
  VMW(4);   // gate A6+B3
  SBAR();
  cvtA(A0);
  mfma8(1, 0);
  VMW(0);   // gate A7
  cvtA(A1);
  mfma8(1, 1);

  // ---- epilogue ----
  float bias[8];
#pragma unroll
  for (int nt = 0; nt < 8; nt++) bias[nt] = b[nt * 16 + qm];
#pragma unroll
  for (int mt = 0; mt < 2; mt++) {
#pragma unroll
    for (int nt = 0; nt < 8; nt++) {
      int col = nt * 16 + qm;
#pragma unroll
      for (int r = 0; r < 4; r++) {
        int node = node0 + wv * 32 + mt * 16 + quad * 4 + r;
        if (node < N_NODES)
          support[(size_t)node * D_OUT + col] = acc[mt][nt][r] + bias[nt];
      }
    }
  }
}

// K1: FULL GEMM || hist+pos_e in one dispatch (gemm blocks first).
// Measured r4: hist co-residency costs the gemm only ~10 us, vs a full
// serial hist dispatch otherwise.  ONE atomic round total (rank captured).
__global__ __launch_bounds__(256, 2) void gemm_hist_kernel(
    const float* __restrict__ input, const short* __restrict__ wt_hi,
    const short* __restrict__ wt_lo, const float* __restrict__ b,
    float* __restrict__ support, const int* __restrict__ erow,
    int* __restrict__ counts, int* __restrict__ pos_e) {
  if (blockIdx.x < GEMM_BLOCKS) {
    gemm_body(blockIdx.x, input, wt_hi, wt_lo, b, support);
  } else {
    int e = (blockIdx.x - GEMM_BLOCKS) * 256 + threadIdx.x;
    if (e < N_EDGES) pos_e[e] = atomicAdd(&counts[erow[e]], 1);
  }
}

// ---------------------------------------------------------------------------
// K2: atomic-free CSR bucket scatter.  Stream-once data uses non-temporal
// loads (keep L2 for offsets + later agg's support); csr_ev store is NT.
// ---------------------------------------------------------------------------
__global__ __launch_bounds__(256) void build_kernel(
    const int* __restrict__ erow, const int* __restrict__ ecol,
    const float* __restrict__ eval, const int* __restrict__ offsets,
    const int* __restrict__ pos_e, long long* __restrict__ csr_ev) {
  int e = blockIdx.x * 256 + threadIdx.x;
  if (e < N_EDGES) {
    int r = __builtin_nontemporal_load(erow + e);
    int c = __builtin_nontemporal_load(ecol + e);
    int vb = __builtin_nontemporal_load((const int*)eval + e);
    int p = __builtin_nontemporal_load(pos_e + e);
    int idx = offsets[r] + p;
    long long packed = (unsigned int)c | ((long long)(unsigned int)vb << 32);
    __builtin_nontemporal_store(packed, csr_ev + idx);
  }
}

// ---------------------------------------------------------------------------
// 3-phase exclusive scan over counts (verified)
// ---------------------------------------------------------------------------
__global__ __launch_bounds__(256) void scan_phase1(const int* __restrict__ counts,
                                                   int* __restrict__ bsums) {
  __shared__ int ts[256];
  int t = threadIdx.x;
  int idx0 = blockIdx.x * SCAN_CHUNK + t * 4;
  int s = 0;
#pragma unroll
  for (int i = 0; i < 4; i++)
    if (idx0 + i < N_NODES) s += counts[idx0 + i];
  ts[t] = s;
  __syncthreads();
#pragma unroll
  for (int off = 128; off > 0; off >>= 1) {
    if (t < off) ts[t] += ts[t + off];
    __syncthreads();
  }
  if (t == 0) bsums[blockIdx.x] = ts[0];
}

__global__ __launch_bounds__(128) void scan_phase2(int* __restrict__ bsums) {
  __shared__ int s[128];
  int t = threadIdx.x;
  int v = (t < SCAN_BLOCKS) ? bsums[t] : 0;
  s[t] = v;
  __syncthreads();
#pragma unroll
  for (int off = 1; off < 128; off <<= 1) {
    int x = (t >= off) ? s[t - off] : 0;
    __syncthreads();
    s[t] += x;
    __syncthreads();
  }
  if (t < SCAN_BLOCKS) bsums[t] = s[t] - v;  // exclusive
}

__global__ __launch_bounds__(256) void scan_phase3(int* __restrict__ counts,
                                                   const int* __restrict__ bsums) {
  __shared__ int ts[256];
  int t = threadIdx.x;
  int b = blockIdx.x;
  int idx0 = b * SCAN_CHUNK + t * 4;
  int v[4];
  int s = 0;
#pragma unroll
  for (int i = 0; i < 4; i++) {
    v[i] = (idx0 + i < N_NODES) ? counts[idx0 + i] : 0;
    s += v[i];
  }
  ts[t] = s;
  __syncthreads();
#pragma unroll
  for (int off = 1; off < 256; off <<= 1) {
    int x = (t >= off) ? ts[t - off] : 0;
    __syncthreads();
    ts[t] += x;
    __syncthreads();
  }
  int run = bsums[b] + ts[t] - s;
#pragma unroll
  for (int i = 0; i < 4; i++) {
    int idx = idx0 + i;
    if (idx < N_NODES) counts[idx] = run;
    run += v[i];
  }
  if (b == 0 && t == 0) counts[N_NODES] = N_EDGES;
}

// ---------------------------------------------------------------------------
// Gather-aggregate + fused tanh (verified round 4 schedule).  csr_ev loads
// are NON-TEMPORAL: 12.8 MB stream-once, keep L2 for the support gathers.
// ---------------------------------------------------------------------------
__global__ __launch_bounds__(256) void agg_kernel(
    const int* __restrict__ offsets, const long long* __restrict__ csr_ev,
    const float* __restrict__ support, float* __restrict__ out) {
  int r = blockIdx.x * 8 + (threadIdx.x >> 5);
  int l4 = (threadIdx.x & 31) * 4;          // feature quad
  int beg = offsets[r];
  int end = offsets[r + 1];
  float4 acc = make_float4(0.f, 0.f, 0.f, 0.f);

  if (end > beg) {
    int ec[8], encol[8];
    float ev[8], env[8];
#pragma unroll
    for (int u = 0; u < 8; u++) {           // prologue batch (predicated)
      int idx = beg + u;
      int c = idx < end ? idx : end - 1;
      long long p = __builtin_nontemporal_load(csr_ev + c);
      ec[u] = (int)(unsigned int)p;
      ev[u] = (idx < end) ? __uint_as_float((unsigned int)(p >> 32)) : 0.f;
    }
    for (int j = beg; j < end; j += 8) {
      int jn = j + 8;
      if (jn < end) {                       // prefetch next batch
#pragma unroll
        for (int u = 0; u < 8; u++) {
          int idx = jn + u;
          int c = idx < end ? idx : end - 1;
          long long p = __builtin_nontemporal_load(csr_ev + c);
          encol[u] = (int)(unsigned int)p;
          env[u] = (idx < end) ? __uint_as_float((unsigned int)(p >> 32)) : 0.f;
        }
      }
      float4 s[8];
#pragma unroll
      for (int u = 0; u < 8; u++)
        s[u] = *(const float4*)(support + (size_t)ec[u] * D_OUT + l4);
#pragma unroll
      for (int u = 0; u < 8; u++) {
        acc.x = fmaf(ev[u], s[u].x, acc.x);
        acc.y = fmaf(ev[u], s[u].y, acc.y);
        acc.z = fmaf(ev[u], s[u].z, acc.z);
        acc.w = fmaf(ev[u], s[u].w, acc.w);
      }
#pragma unroll
      for (int u = 0; u < 8; u++) { ec[u] = encol[u]; ev[u] = env[u]; }
    }
  }
  *(float4*)(out + (size_t)r * D_OUT + l4) =
      make_float4(tanhf(acc.x), tanhf(acc.y), tanhf(acc.z), tanhf(acc.w));
}

extern "C" void kernel_launch(void* const* d_in, const int* in_sizes, int n_in,
                              void* d_out, int out_size, void* d_ws, size_t ws_size,
                              hipStream_t stream) {
  const float* input = (const float*)d_in[0];
  const int* erow = (const int*)d_in[1];
  const int* ecol = (const int*)d_in[2];
  const float* eval = (const float*)d_in[3];
  const float* W = (const float*)d_in[4];
  const float* b = (const float*)d_in[5];
  float* out = (float*)d_out;

  char* ws = (char*)d_ws;
  float* support = (float*)(ws + OFF_SUPPORT);
  int* counts = (int*)(ws + OFF_COUNTS);  // becomes offsets after scan
  long long* csr_ev = (long long*)(ws + OFF_CSREV);
  int* bsums = (int*)(ws + OFF_BSUMS);
  short* wt_hi = (short*)(ws + OFF_WTHI);
  short* wt_lo = (short*)(ws + OFF_WTLO);
  int* pos_e = (int*)d_out;  // d_out as scratch; agg overwrites it last

  // K0: convert W once + zero counts (no separate memset dispatch)
  hipLaunchKernelGGL(wconv_kernel, dim3((D_IN * D_OUT) / 256), dim3(256), 0,
                     stream, W, wt_hi, wt_lo, counts);
  // K1: full MFMA-GEMM || full histogram (one dispatch, overlapped)
  hipLaunchKernelGGL(gemm_hist_kernel, dim3(GEMM_BLOCKS + EDGE_BLOCKS),
                     dim3(256), 0, stream, input, wt_hi, wt_lo, b, support,
                     erow, counts, pos_e);
  // exclusive scan: counts -> offsets
  hipLaunchKernelGGL(scan_phase1, dim3(SCAN_BLOCKS), dim3(256), 0, stream,
                     counts, bsums);
  hipLaunchKernelGGL(scan_phase2, dim3(1), dim3(128), 0, stream, bsums);
  hipLaunchKernelGGL(scan_phase3, dim3(SCAN_BLOCKS), dim3(256), 0, stream,
                     counts, bsums);
  // K2: atomic-free CSR bucket scatter (NT streams)
  hipLaunchKernelGGL(build_kernel, dim3(EDGE_BLOCKS), dim3(256), 0, stream,
                     erow, ecol, eval, counts, pos_e, csr_ev);
  // out = tanh(A_csr * support)
  hipLaunchKernelGGL(agg_kernel, dim3(N_NODES / 8), dim3(256), 0, stream,
                     counts, csr_ev, support, out);
}